// Round 8
// baseline (561.940 us; speedup 1.0000x reference)
//
#include <hip/hip_runtime.h>
#include <hip/hip_bf16.h>
#include <cstdint>

#define NN 20000
#define NEg 320000

typedef short bf16x8 __attribute__((ext_vector_type(8)));
typedef float f32x4 __attribute__((ext_vector_type(4)));

// wT (u16 elements) layout: MLP weights transposed n-major, split hi/lo bf16
#define O_M1H 0
#define O_M1L 512
#define O_M2H 1024
#define O_M2L 5120
#define O_M3H 9216
#define O_M3L 13312
#define O_M4H 17408
#define O_M4L 33792
#define O_W0  50176
#define O_W1  54272
#define O_WL0 58368
#define O_WL1 66560
#define WT_TOT 74752

__device__ __forceinline__ float b2f(unsigned short u){
  unsigned int v = ((unsigned int)u) << 16;
  float f; __builtin_memcpy(&f, &v, 4); return f;
}
__device__ __forceinline__ float blo(unsigned int d){   // low u16 as bf16
  unsigned int v = d << 16; float f; __builtin_memcpy(&f, &v, 4); return f;
}
__device__ __forceinline__ float bhi(unsigned int d){   // high u16 as bf16
  unsigned int v = d & 0xffff0000u; float f; __builtin_memcpy(&f, &v, 4); return f;
}
__device__ __forceinline__ unsigned short f2b(float f){
  unsigned int x; __builtin_memcpy(&x, &f, 4);
  x += 0x7FFFu + ((x >> 16) & 1u);
  return (unsigned short)(x >> 16);
}
__device__ __forceinline__ float silu_f(float x){ return x / (1.f + __expf(-x)); }

__global__ void k_zero(int* __restrict__ p, int n){
  int i = blockIdx.x*256 + threadIdx.x;
  if (i < n) p[i] = 0;
}

__global__ void k_fill32(float* __restrict__ p, int n, float val){
  int i = blockIdx.x*256 + threadIdx.x;
  if (i < n) p[i] = val;
}

__global__ void k_prep(const float* __restrict__ M1, const float* __restrict__ M2,
                       const float* __restrict__ M3, const float* __restrict__ M4,
                       const float* __restrict__ W0, const float* __restrict__ W1,
                       const float* __restrict__ Wl0, const float* __restrict__ Wl1,
                       unsigned short* __restrict__ wT){
  int i = blockIdx.x*256 + threadIdx.x;
  if (i >= WT_TOT) return;
  float v; bool lo = false;
  if (i < O_M1L){ int t=i;        int n=t>>3, k=t&7;  v = M1[k*64+n]; }
  else if (i < O_M2H){ int t=i-O_M1L; int n=t>>3, k=t&7;  v = M1[k*64+n];  lo = true; }
  else if (i < O_M2L){ int t=i-O_M2H; int n=t>>6, k=t&63; v = M2[k*64+n]; }
  else if (i < O_M3H){ int t=i-O_M2L; int n=t>>6, k=t&63; v = M2[k*64+n]; lo = true; }
  else if (i < O_M3L){ int t=i-O_M3H; int n=t>>6, k=t&63; v = M3[k*64+n]; }
  else if (i < O_M4H){ int t=i-O_M3L; int n=t>>6, k=t&63; v = M3[k*64+n]; lo = true; }
  else if (i < O_M4L){ int t=i-O_M4H; int n=t>>6, k=t&63; v = M4[k*256+n]; }
  else if (i < O_W0 ){ int t=i-O_M4L; int n=t>>6, k=t&63; v = M4[k*256+n]; lo = true; }
  else if (i < O_W1 ){ v = W0[i-O_W0]; }
  else if (i < O_WL0){ v = W1[i-O_W1]; }
  else if (i < O_WL1){ v = Wl0[i-O_WL0]; }
  else               { v = Wl1[i-O_WL1]; }
  unsigned short h = f2b(v);
  wT[i] = lo ? f2b(v - b2f(h)) : h;
}

__global__ void k_hist(const int* __restrict__ recv, int* __restrict__ deg){
  int e = blockIdx.x*256 + threadIdx.x;
  if (e < NEg){
    int r = recv[e];
    if ((unsigned)r < NN) atomicAdd(&deg[r], 1);
  }
}

__global__ __launch_bounds__(1024) void k_scan(int* __restrict__ cursor, int* __restrict__ off){
  __shared__ int part[1024];
  int t = threadIdx.x;
  int base = t*20;
  int loc[20]; int s = 0;
  #pragma unroll
  for (int i=0;i<20;i++){ int idx=base+i; int d = (idx<NN)? cursor[idx] : 0; loc[i]=d; s+=d; }
  part[t] = s; __syncthreads();
  for (int d=1; d<1024; d<<=1){
    int v = part[t];
    int add = (t>=d)? part[t-d] : 0;
    __syncthreads();
    part[t] = v + add;
    __syncthreads();
  }
  int run = part[t] - s;
  #pragma unroll
  for (int i=0;i<20;i++){ int idx=base+i; if (idx<NN){ off[idx]=run; cursor[idx]=run; run+=loc[i]; } }
  if (t==1023) off[NN] = part[1023];
}

__global__ void k_fill(const int* __restrict__ recv, int* __restrict__ cursor, int* __restrict__ eid){
  int e = blockIdx.x*256 + threadIdx.x;
  if (e < NEg){
    int r = recv[e];
    if ((unsigned)r < NN){
      int p = atomicAdd(&cursor[r], 1);
      if ((unsigned)p < NEg) eid[p] = e;
    }
  }
}

// up-projection -> sv bf16, interleaved layout [n][u][xs, xv0, xv1, xv2] * 0.125
__global__ __launch_bounds__(256) void k_upproj(const float* __restrict__ nf,
    const unsigned short* __restrict__ wT, unsigned short* __restrict__ sv){
  __shared__ float x[256];
  const unsigned short* W0b = wT + O_W0;
  const unsigned short* W1b = wT + O_W1;
  int n = blockIdx.x, t = threadIdx.x;
  x[t] = nf[n*256 + t];
  __syncthreads();
  float acc = 0.f;
  int slot;
  if (t < 64){
    for (int u=0; u<64; u++) acc += x[u] * b2f(W0b[u*64 + t]);
    slot = t*4;
  } else {
    int mm = (t-64) >> 6, vo = (t-64) & 63;
    for (int u=0; u<64; u++) acc += x[64 + 3*u + mm] * b2f(W1b[u*64 + vo]);
    slot = vo*4 + 1 + mm;
  }
  sv[n*256 + slot] = f2b(acc * 0.125f);
}

// one 64-ch dense layer + silu, split activations (hi/lo LDS) x split weights (3-product)
__device__ __forceinline__ void dense64_silu(const unsigned short* src,
                                             const unsigned short* WH, const unsigned short* WL,
                                             unsigned short* dst, int m, int q){
  bf16x8 ah0 = *(const bf16x8*)(src + m*72 + q*8);
  bf16x8 ah1 = *(const bf16x8*)(src + m*72 + 32 + q*8);
  bf16x8 al0 = *(const bf16x8*)(src + 1152 + m*72 + q*8);
  bf16x8 al1 = *(const bf16x8*)(src + 1152 + m*72 + 32 + q*8);
  const f32x4 zero = {0.f,0.f,0.f,0.f};
  #pragma unroll
  for (int nt = 0; nt < 4; nt++){
    bf16x8 bh0 = *(const bf16x8*)(WH + (nt*16 + m)*64 + q*8);
    bf16x8 bh1 = *(const bf16x8*)(WH + (nt*16 + m)*64 + 32 + q*8);
    bf16x8 bl0 = *(const bf16x8*)(WL + (nt*16 + m)*64 + q*8);
    bf16x8 bl1 = *(const bf16x8*)(WL + (nt*16 + m)*64 + 32 + q*8);
    f32x4 c = __builtin_amdgcn_mfma_f32_16x16x32_bf16(ah0, bh0, zero, 0, 0, 0);
    c = __builtin_amdgcn_mfma_f32_16x16x32_bf16(ah1, bh1, c, 0, 0, 0);
    c = __builtin_amdgcn_mfma_f32_16x16x32_bf16(al0, bh0, c, 0, 0, 0);
    c = __builtin_amdgcn_mfma_f32_16x16x32_bf16(al1, bh1, c, 0, 0, 0);
    c = __builtin_amdgcn_mfma_f32_16x16x32_bf16(ah0, bl0, c, 0, 0, 0);
    c = __builtin_amdgcn_mfma_f32_16x16x32_bf16(ah1, bl1, c, 0, 0, 0);
    #pragma unroll
    for (int r = 0; r < 4; r++){
      float v = silu_f(c[r] * 0.125f);
      unsigned short hi = f2b(v);
      unsigned short lo = f2b(v - b2f(hi));
      dst[(q*4+r)*72 + nt*16 + m] = hi;
      dst[1152 + (q*4+r)*72 + nt*16 + m] = lo;
    }
  }
}

// ---------------- SPLIT PATH ----------------
// edge-parallel MFMA MLP -> tpwb positional, INTERLEAVED [row][u][g] bf16 (direct C-frag stores)
__global__ __launch_bounds__(256) void k_mlp_s(const int* __restrict__ off, const int* __restrict__ eid,
    const float* __restrict__ ef, const unsigned short* __restrict__ wT,
    unsigned short* __restrict__ tpwb, int n0, int n1, int cap){
  __shared__ __align__(16) unsigned short h[4][2][1152];   // 18432 B total
  const int tid = threadIdx.x;
  const int w = tid >> 6, l = tid & 63;
  const int m = l & 15, q = l >> 4;
  int pos0 = off[n0], pos1 = off[n1];
  if (pos0 < 0) pos0 = 0; if (pos1 > NEg) pos1 = NEg; if (pos1 < pos0) pos1 = pos0;
  const int pos_end = min(pos1, pos0 + cap);
  const int p0 = pos0 + blockIdx.x*64 + w*16;
  if (pos0 + (int)blockIdx.x*64 >= pos_end) return;
  const int lim = min(16, max(0, pos_end - p0));
  const f32x4 zero = {0.f,0.f,0.f,0.f};

  // layer 1: (16x8)@(8x64), K zero-padded to 32, split 3-product
  bf16x8 ah = {0,0,0,0,0,0,0,0}, al = {0,0,0,0,0,0,0,0};
  if (q == 0 && m < lim){
    int e = eid[p0 + m]; if ((unsigned)e >= NEg) e = 0;
    const float* efp = ef + (size_t)e * 8;
    float4 fa = *(const float4*)(efp);
    float4 fb = *(const float4*)(efp + 4);
    float av8[8] = {fa.x, fa.y, fa.z, fa.w, fb.x, fb.y, fb.z, fb.w};
    #pragma unroll
    for (int j = 0; j < 8; j++){
      unsigned short hb = f2b(av8[j]);
      ah[j] = (short)hb;
      al[j] = (short)f2b(av8[j] - b2f(hb));
    }
  }
  #pragma unroll
  for (int nt = 0; nt < 4; nt++){
    bf16x8 bh = {0,0,0,0,0,0,0,0}, bl = {0,0,0,0,0,0,0,0};
    if (q == 0){
      bh = *(const bf16x8*)(wT + O_M1H + (nt*16 + m)*8);
      bl = *(const bf16x8*)(wT + O_M1L + (nt*16 + m)*8);
    }
    f32x4 c = __builtin_amdgcn_mfma_f32_16x16x32_bf16(ah, bh, zero, 0, 0, 0);
    c = __builtin_amdgcn_mfma_f32_16x16x32_bf16(al, bh, c, 0, 0, 0);
    c = __builtin_amdgcn_mfma_f32_16x16x32_bf16(ah, bl, c, 0, 0, 0);
    #pragma unroll
    for (int r = 0; r < 4; r++){
      float v = silu_f(c[r] * 0.35355339059f);
      unsigned short hi = f2b(v);
      unsigned short lo = f2b(v - b2f(hi));
      h[w][0][(q*4+r)*72 + nt*16 + m] = hi;
      h[w][1][(q*4+r)*72 + nt*16 + m] = lo;
    }
  }
  dense64_silu(&h[w][0][0], wT + O_M2H, wT + O_M2L, &h[w][0][0], m, q);
  dense64_silu(&h[w][0][0], wT + O_M3H, wT + O_M3L, &h[w][0][0], m, q);
  // layer 4: direct store to global, interleaved [row][u][g]; col=nt*16+m -> g=nt>>2, u=(nt&3)*16+m
  {
    const unsigned short* src = &h[w][0][0];
    bf16x8 ah0 = *(const bf16x8*)(src + m*72 + q*8);
    bf16x8 ah1 = *(const bf16x8*)(src + m*72 + 32 + q*8);
    bf16x8 al0 = *(const bf16x8*)(src + 1152 + m*72 + q*8);
    bf16x8 al1 = *(const bf16x8*)(src + 1152 + m*72 + 32 + q*8);
    const int lb = p0 - pos0;
    #pragma unroll
    for (int nt = 0; nt < 16; nt++){
      bf16x8 bh0 = *(const bf16x8*)(wT + O_M4H + (nt*16 + m)*64 + q*8);
      bf16x8 bh1 = *(const bf16x8*)(wT + O_M4H + (nt*16 + m)*64 + 32 + q*8);
      bf16x8 bl0 = *(const bf16x8*)(wT + O_M4L + (nt*16 + m)*64 + q*8);
      bf16x8 bl1 = *(const bf16x8*)(wT + O_M4L + (nt*16 + m)*64 + 32 + q*8);
      f32x4 c = __builtin_amdgcn_mfma_f32_16x16x32_bf16(ah0, bh0, zero, 0, 0, 0);
      c = __builtin_amdgcn_mfma_f32_16x16x32_bf16(ah1, bh1, c, 0, 0, 0);
      c = __builtin_amdgcn_mfma_f32_16x16x32_bf16(al0, bh0, c, 0, 0, 0);
      c = __builtin_amdgcn_mfma_f32_16x16x32_bf16(al1, bh1, c, 0, 0, 0);
      c = __builtin_amdgcn_mfma_f32_16x16x32_bf16(ah0, bl0, c, 0, 0, 0);
      c = __builtin_amdgcn_mfma_f32_16x16x32_bf16(ah1, bl1, c, 0, 0, 0);
      const int slot = ((nt & 3)*16 + m)*4 + (nt >> 2);
      #pragma unroll
      for (int r = 0; r < 4; r++){
        const int row = q*4 + r;
        if (row < lim)
          tpwb[(size_t)(lb + row)*256 + slot] = f2b(c[r] * 0.125f);
      }
    }
  }
}

// wave-per-node gather: per edge, lane l does ONE uint2 load from tpwb + ONE from sv
__global__ __launch_bounds__(256) void k_gather_s(const int* __restrict__ off, const int* __restrict__ eid,
    const int* __restrict__ sender, const float* __restrict__ ea,
    const unsigned short* __restrict__ sv, const unsigned short* __restrict__ tpwb,
    const unsigned short* __restrict__ wT, float* __restrict__ out, int n0, int n1, int cap){
  __shared__ float msg[4][512];
  const int tid = threadIdx.x;
  const int w = tid >> 6, l = tid & 63;
  const int n = n0 + blockIdx.x*4 + w;
  if (n >= n1) return;
  int pos0 = off[n0];
  int s0 = off[n];
  int cnt = off[n+1] - s0;
  if (s0 < 0) s0 = 0; if (s0 > NEg) s0 = NEg;
  if (cnt < 0) cnt = 0; if (cnt > 512) cnt = 512;
  if (s0 + cnt > NEg) cnt = NEg - s0;
  const int lb = s0 - pos0;

  float as0 = 0.f, as1 = 0.f;
  float av00=0.f, av01=0.f, av02=0.f, av10=0.f, av11=0.f, av12=0.f;

  int e = 0, sd = 0;
  if (cnt > 0){
    e = eid[s0]; if ((unsigned)e >= NEg) e = 0;
    sd = sender[e]; if ((unsigned)sd >= NN) sd = 0;
  }
  for (int i = 0; i < cnt; i++){
    const int ec = e, sc = sd;
    if (i + 1 < cnt){
      e = eid[s0 + i + 1]; if ((unsigned)e >= NEg) e = 0;
      sd = sender[e]; if ((unsigned)sd >= NN) sd = 0;
    }
    int ti = lb + i; if ((unsigned)ti >= (unsigned)cap) ti = 0;
    const uint2 tw = *(const uint2*)(tpwb + (size_t)ti * 256 + l*4);
    const uint2 sx = *(const uint2*)(sv + (size_t)sc * 256 + l*4);
    const float4 ev = *(const float4*)(ea + (size_t)ec * 4);
    const float w0 = blo(tw.x), w1 = bhi(tw.x), w2 = blo(tw.y), w3 = bhi(tw.y);
    const float xs = blo(sx.x), xv0 = bhi(sx.x), xv1 = blo(sx.y), xv2 = bhi(sx.y);
    as0 += w0 * xs * ev.x;
    as1 += w3 * (xv0*ev.y + xv1*ev.z + xv2*ev.w);
    const float t1 = w1 * xs;
    av00 += t1*ev.y; av01 += t1*ev.z; av02 += t1*ev.w;
    const float t2 = w2 * ev.x;
    av10 += t2*xv0; av11 += t2*xv1; av12 += t2*xv2;
  }
  msg[w][l]       = as0;
  msg[w][64 + l]  = as1 * 0.57735026919f;    // INV_SQRT3
  msg[w][128+3*l] = av00; msg[w][128+3*l+1] = av01; msg[w][128+3*l+2] = av02;
  msg[w][320+3*l] = av10; msg[w][320+3*l+1] = av11; msg[w][320+3*l+2] = av12;

  const unsigned short* Wl0b = wT + O_WL0;
  const unsigned short* Wl1b = wT + O_WL1;
  float accS = 0.f, ac0 = 0.f, ac1 = 0.f, ac2 = 0.f;
  for (int up = 0; up < 128; up++){
    accS += msg[w][up] * b2f(Wl0b[up*64 + l]);
    const float wv = b2f(Wl1b[up*64 + l]);
    ac0 += msg[w][128 + 3*up]     * wv;
    ac1 += msg[w][128 + 3*up + 1] * wv;
    ac2 += msg[w][128 + 3*up + 2] * wv;
  }
  const float C = 0.0055242717280199f;       // (1/sqrt(128)) / 16
  float* op = out + (size_t)n * 256;
  op[l] = accS * C;
  op[64 + 3*l]     = ac0 * C;
  op[64 + 3*l + 1] = ac1 * C;
  op[64 + 3*l + 2] = ac2 * C;
}

// ---------------- FUSED FALLBACK (round-6 numerics, new sv layout) ----------------
__global__ __launch_bounds__(256) void k_fused(const int* __restrict__ off, const int* __restrict__ eid,
    const int* __restrict__ sender, const float* __restrict__ ea,
    const float* __restrict__ ef, const unsigned short* __restrict__ sv,
    const float* __restrict__ nf, const unsigned short* __restrict__ wT,
    float* __restrict__ out, int mode){
  __shared__ __align__(16) unsigned short h[4][2][1152];
  __shared__ __align__(16) unsigned short tpt[4][16][264];
  __shared__ float msg[4][512];
  __shared__ float4 eab[4][16];
  __shared__ int sb[4][16];

  const int tid = threadIdx.x;
  const int w = tid >> 6, l = tid & 63;
  const int m = l & 15, q = l >> 4;
  const int n = blockIdx.x*4 + w;
  const f32x4 zero = {0.f,0.f,0.f,0.f};

  int s0 = off[n];
  int cnt = off[n+1] - s0;
  if (s0 < 0) s0 = 0; if (s0 > NEg) s0 = NEg;
  if (cnt < 0) cnt = 0; if (cnt > 512) cnt = 512;
  if (s0 + cnt > NEg) cnt = NEg - s0;

  float as0 = 0.f, as1 = 0.f;
  float av00=0.f, av01=0.f, av02=0.f, av10=0.f, av11=0.f, av12=0.f;

  const int ntile = (cnt + 15) >> 4;
  for (int tl = 0; tl < ntile; tl++){
    const int base = s0 + tl*16;
    const int rows = min(16, cnt - tl*16);
    bf16x8 ah = {0,0,0,0,0,0,0,0}, al = {0,0,0,0,0,0,0,0};
    if (q == 0){
      int e = 0, sd = 0;
      if (m < rows){
        e = eid[base + m]; if ((unsigned)e >= NEg) e = 0;
        sd = sender[e];    if ((unsigned)sd >= NN) sd = 0;
        const float* efp = ef + (size_t)e * 8;
        float4 fa = *(const float4*)(efp);
        float4 fb = *(const float4*)(efp + 4);
        float av8[8] = {fa.x, fa.y, fa.z, fa.w, fb.x, fb.y, fb.z, fb.w};
        #pragma unroll
        for (int j = 0; j < 8; j++){
          unsigned short hb = f2b(av8[j]);
          ah[j] = (short)hb;
          al[j] = (short)f2b(av8[j] - b2f(hb));
        }
        eab[w][m] = *(const float4*)(ea + (size_t)e * 4);
      }
      sb[w][m] = sd;
    }
    #pragma unroll
    for (int nt = 0; nt < 4; nt++){
      bf16x8 bh = {0,0,0,0,0,0,0,0}, bl = {0,0,0,0,0,0,0,0};
      if (q == 0){
        bh = *(const bf16x8*)(wT + O_M1H + (nt*16 + m)*8);
        bl = *(const bf16x8*)(wT + O_M1L + (nt*16 + m)*8);
      }
      f32x4 c = __builtin_amdgcn_mfma_f32_16x16x32_bf16(ah, bh, zero, 0, 0, 0);
      c = __builtin_amdgcn_mfma_f32_16x16x32_bf16(al, bh, c, 0, 0, 0);
      c = __builtin_amdgcn_mfma_f32_16x16x32_bf16(ah, bl, c, 0, 0, 0);
      #pragma unroll
      for (int r = 0; r < 4; r++){
        float v = silu_f(c[r] * 0.35355339059f);
        unsigned short hi = f2b(v);
        unsigned short lo = f2b(v - b2f(hi));
        h[w][0][(q*4+r)*72 + nt*16 + m] = hi;
        h[w][1][(q*4+r)*72 + nt*16 + m] = lo;
      }
    }
    dense64_silu(&h[w][0][0], wT + O_M2H, wT + O_M2L, &h[w][0][0], m, q);
    dense64_silu(&h[w][0][0], wT + O_M3H, wT + O_M3L, &h[w][0][0], m, q);
    {
      const unsigned short* src = &h[w][0][0];
      bf16x8 ah0 = *(const bf16x8*)(src + m*72 + q*8);
      bf16x8 ah1 = *(const bf16x8*)(src + m*72 + 32 + q*8);
      bf16x8 al0 = *(const bf16x8*)(src + 1152 + m*72 + q*8);
      bf16x8 al1 = *(const bf16x8*)(src + 1152 + m*72 + 32 + q*8);
      #pragma unroll
      for (int nt = 0; nt < 16; nt++){
        bf16x8 bh0 = *(const bf16x8*)(wT + O_M4H + (nt*16 + m)*64 + q*8);
        bf16x8 bh1 = *(const bf16x8*)(wT + O_M4H + (nt*16 + m)*64 + 32 + q*8);
        bf16x8 bl0 = *(const bf16x8*)(wT + O_M4L + (nt*16 + m)*64 + q*8);
        bf16x8 bl1 = *(const bf16x8*)(wT + O_M4L + (nt*16 + m)*64 + 32 + q*8);
        f32x4 c = __builtin_amdgcn_mfma_f32_16x16x32_bf16(ah0, bh0, zero, 0, 0, 0);
        c = __builtin_amdgcn_mfma_f32_16x16x32_bf16(ah1, bh1, c, 0, 0, 0);
        c = __builtin_amdgcn_mfma_f32_16x16x32_bf16(al0, bh0, c, 0, 0, 0);
        c = __builtin_amdgcn_mfma_f32_16x16x32_bf16(al1, bh1, c, 0, 0, 0);
        c = __builtin_amdgcn_mfma_f32_16x16x32_bf16(ah0, bl0, c, 0, 0, 0);
        c = __builtin_amdgcn_mfma_f32_16x16x32_bf16(ah1, bl1, c, 0, 0, 0);
        #pragma unroll
        for (int r = 0; r < 4; r++)
          tpt[w][q*4+r][nt*16 + m] = f2b(c[r] * 0.125f);
      }
    }
    for (int i = 0; i < rows; i++){
      const int sd = sb[w][i];
      const float4 ev = eab[w][i];
      float xs, xv0, xv1, xv2;
      if (mode == 0){
        const uint2 sx = *(const uint2*)(sv + (size_t)sd * 256 + l*4);
        xs = blo(sx.x); xv0 = bhi(sx.x); xv1 = blo(sx.y); xv2 = bhi(sx.y);
      } else {
        const float* nfp = nf + (size_t)sd * 256;
        const unsigned short* W0b = wT + O_W0;
        const unsigned short* W1b = wT + O_W1;
        float a0 = 0.f, a1 = 0.f, a2 = 0.f, a3 = 0.f;
        for (int k = 0; k < 64; k++){
          const float w0k = b2f(W0b[k*64 + l]);
          const float w1k = b2f(W1b[k*64 + l]);
          a0 += nfp[k] * w0k;
          a1 += nfp[64 + 3*k]     * w1k;
          a2 += nfp[64 + 3*k + 1] * w1k;
          a3 += nfp[64 + 3*k + 2] * w1k;
        }
        xs = a0 * 0.125f; xv0 = a1 * 0.125f; xv1 = a2 * 0.125f; xv2 = a3 * 0.125f;
      }
      const float w0 = b2f(tpt[w][i][l]);
      const float w1 = b2f(tpt[w][i][64 + l]);
      const float w2 = b2f(tpt[w][i][128 + l]);
      const float w3 = b2f(tpt[w][i][192 + l]);
      as0 += w0 * xs * ev.x;
      as1 += w3 * (xv0*ev.y + xv1*ev.z + xv2*ev.w);
      const float t1 = w1 * xs;
      av00 += t1*ev.y; av01 += t1*ev.z; av02 += t1*ev.w;
      const float t2 = w2 * ev.x;
      av10 += t2*xv0; av11 += t2*xv1; av12 += t2*xv2;
    }
  }
  msg[w][l]       = as0;
  msg[w][64 + l]  = as1 * 0.57735026919f;
  msg[w][128+3*l] = av00; msg[w][128+3*l+1] = av01; msg[w][128+3*l+2] = av02;
  msg[w][320+3*l] = av10; msg[w][320+3*l+1] = av11; msg[w][320+3*l+2] = av12;

  const unsigned short* Wl0b = wT + O_WL0;
  const unsigned short* Wl1b = wT + O_WL1;
  float accS = 0.f, ac0 = 0.f, ac1 = 0.f, ac2 = 0.f;
  for (int up = 0; up < 128; up++){
    accS += msg[w][up] * b2f(Wl0b[up*64 + l]);
    const float wv = b2f(Wl1b[up*64 + l]);
    ac0 += msg[w][128 + 3*up]     * wv;
    ac1 += msg[w][128 + 3*up + 1] * wv;
    ac2 += msg[w][128 + 3*up + 2] * wv;
  }
  const float C = 0.0055242717280199f;
  float* op = out + (size_t)n * 256;
  op[l] = accS * C;
  op[64 + 3*l]     = ac0 * C;
  op[64 + 3*l + 1] = ac1 * C;
  op[64 + 3*l + 2] = ac2 * C;
}

extern "C" void kernel_launch(void* const* d_in, const int* in_sizes, int n_in,
                              void* d_out, int out_size, void* d_ws, size_t ws_size,
                              hipStream_t stream){
  float* out = (float*)d_out;
  const int nblk_out = (out_size + 255) / 256;

  static const long long exp_sizes[15] = {320000, 5120000, 1280000, 2560000, 640000,
                                          4096, 4096, 512, 4096, 4096, 16384, 8192, 8192,
                                          65536, 65536};
  bool ok = (n_in == 15) && (out_size == 5120000);
  if (ok) for (int i = 0; i < 15; i++) if ((long long)in_sizes[i] != exp_sizes[i]) ok = false;
  if (!ok){
    k_fill32<<<nblk_out, 256, 0, stream>>>(out, out_size, 100.0f);
    return;
  }

  const float* node_feats = (const float*)d_in[1];
  const float* edge_attrs = (const float*)d_in[2];
  const float* edge_feats = (const float*)d_in[3];
  const int* edge_index = (const int*)d_in[4];
  const float* Wup0 = (const float*)d_in[5];
  const float* Wup1 = (const float*)d_in[6];
  const float* M1 = (const float*)d_in[7];
  const float* M2 = (const float*)d_in[8];
  const float* M3 = (const float*)d_in[9];
  const float* M4 = (const float*)d_in[10];
  const float* Wl0 = (const float*)d_in[11];
  const float* Wl1 = (const float*)d_in[12];
  const int* sender = edge_index;
  const int* recv   = edge_index + NEg;

  const size_t SZ_OFF = 80128, SZ_CUR = 80128, SZ_EID = 1280000, SZ_WT = WT_TOT*2;
  const size_t SZ_SV = 10240000;
  const size_t foot_csr  = SZ_OFF + SZ_CUR + SZ_EID + SZ_WT;       // 1,589,760
  const size_t foot_full = foot_csr + SZ_SV;                       // 11,829,760
  const size_t foot_b2   = foot_full + (size_t)12288*512;          // 18.1 MB
  const size_t foot_b    = foot_full + (size_t)45056*512;          // 34.9 MB
  const size_t foot_a    = foot_full + (size_t)NEg*512;            // 175.7 MB

  if (ws_size < foot_csr){
    k_fill32<<<nblk_out, 256, 0, stream>>>(out, out_size, 50.0f);
    return;
  }
  char* ws = (char*)d_ws;
  int* off    = (int*)(ws);
  int* cursor = (int*)(ws + SZ_OFF);
  int* eid    = (int*)(ws + SZ_OFF + SZ_CUR);
  unsigned short* wT   = (unsigned short*)(ws + SZ_OFF + SZ_CUR + SZ_EID);
  unsigned short* sv   = (unsigned short*)(ws + foot_csr);
  unsigned short* tpwb = (unsigned short*)(ws + foot_full);

  k_zero<<<(NN+255)/256, 256, 0, stream>>>(cursor, NN);
  k_prep<<<(WT_TOT+255)/256, 256, 0, stream>>>(M1, M2, M3, M4, Wup0, Wup1, Wl0, Wl1, wT);
  k_hist<<<NEg/256, 256, 0, stream>>>(recv, cursor);
  k_scan<<<1, 1024, 0, stream>>>(cursor, off);
  k_fill<<<NEg/256, 256, 0, stream>>>(recv, cursor, eid);

  if (ws_size >= foot_b2){
    int nchunk, cap;
    if (ws_size >= foot_a){ nchunk = 1;  cap = NEg;   }
    else if (ws_size >= foot_b){ nchunk = 8;  cap = 45056; }
    else { nchunk = 32; cap = 12288; }
    const int chn = NN / nchunk;
    k_upproj<<<NN, 256, 0, stream>>>(node_feats, wT, sv);
    for (int c = 0; c < nchunk; c++){
      const int n0 = c*chn, n1 = n0 + chn;
      k_mlp_s<<<cap/64, 256, 0, stream>>>(off, eid, edge_feats, wT, tpwb, n0, n1, cap);
      k_gather_s<<<(chn + 3)/4, 256, 0, stream>>>(off, eid, sender, edge_attrs, sv, tpwb,
                                                  wT, out, n0, n1, cap);
    }
  } else {
    const int mode = (ws_size >= foot_full) ? 0 : 1;
    if (mode == 0)
      k_upproj<<<NN, 256, 0, stream>>>(node_feats, wT, sv);
    k_fused<<<NN/4, 256, 0, stream>>>(off, eid, sender, edge_attrs, edge_feats,
                                      sv, node_feats, wT, out, mode);
  }
}

// Round 10
// 541.935 us; speedup vs baseline: 1.0369x; 1.0369x over previous
//
#include <hip/hip_runtime.h>
#include <hip/hip_bf16.h>
#include <cstdint>

#define NN 20000
#define NEg 320000

typedef short bf16x8 __attribute__((ext_vector_type(8)));
typedef float f32x4 __attribute__((ext_vector_type(4)));

// wT (u16 elements) layout: MLP weights transposed n-major, split hi/lo bf16
#define O_M1H 0
#define O_M1L 512
#define O_M2H 1024
#define O_M2L 5120
#define O_M3H 9216
#define O_M3L 13312
#define O_M4H 17408
#define O_M4L 33792
#define O_W0  50176
#define O_W1  54272
#define O_WL0 58368
#define O_WL1 66560
#define WT_TOT 74752

__device__ __forceinline__ float b2f(unsigned short u){
  unsigned int v = ((unsigned int)u) << 16;
  float f; __builtin_memcpy(&f, &v, 4); return f;
}
__device__ __forceinline__ float blo(unsigned int d){
  unsigned int v = d << 16; float f; __builtin_memcpy(&f, &v, 4); return f;
}
__device__ __forceinline__ float bhi(unsigned int d){
  unsigned int v = d & 0xffff0000u; float f; __builtin_memcpy(&f, &v, 4); return f;
}
__device__ __forceinline__ unsigned short f2b(float f){
  unsigned int x; __builtin_memcpy(&x, &f, 4);
  x += 0x7FFFu + ((x >> 16) & 1u);
  return (unsigned short)(x >> 16);
}
__device__ __forceinline__ float silu_f(float x){ return x / (1.f + __expf(-x)); }

__global__ void k_zero(int* __restrict__ p, int n){
  int i = blockIdx.x*256 + threadIdx.x;
  if (i < n) p[i] = 0;
}

__global__ void k_fill32(float* __restrict__ p, int n, float val){
  int i = blockIdx.x*256 + threadIdx.x;
  if (i < n) p[i] = val;
}

__global__ void k_prep(const float* __restrict__ M1, const float* __restrict__ M2,
                       const float* __restrict__ M3, const float* __restrict__ M4,
                       const float* __restrict__ W0, const float* __restrict__ W1,
                       const float* __restrict__ Wl0, const float* __restrict__ Wl1,
                       unsigned short* __restrict__ wT){
  int i = blockIdx.x*256 + threadIdx.x;
  if (i >= WT_TOT) return;
  float v; bool lo = false;
  if (i < O_M1L){ int t=i;        int n=t>>3, k=t&7;  v = M1[k*64+n]; }
  else if (i < O_M2H){ int t=i-O_M1L; int n=t>>3, k=t&7;  v = M1[k*64+n];  lo = true; }
  else if (i < O_M2L){ int t=i-O_M2H; int n=t>>6, k=t&63; v = M2[k*64+n]; }
  else if (i < O_M3H){ int t=i-O_M2L; int n=t>>6, k=t&63; v = M2[k*64+n]; lo = true; }
  else if (i < O_M3L){ int t=i-O_M3H; int n=t>>6, k=t&63; v = M3[k*64+n]; }
  else if (i < O_M4H){ int t=i-O_M3L; int n=t>>6, k=t&63; v = M3[k*64+n]; lo = true; }
  else if (i < O_M4L){ int t=i-O_M4H; int n=t>>6, k=t&63; v = M4[k*256+n]; }
  else if (i < O_W0 ){ int t=i-O_M4L; int n=t>>6, k=t&63; v = M4[k*256+n]; lo = true; }
  else if (i < O_W1 ){ v = W0[i-O_W0]; }
  else if (i < O_WL0){ v = W1[i-O_W1]; }
  else if (i < O_WL1){ v = Wl0[i-O_WL0]; }
  else               { v = Wl1[i-O_WL1]; }
  unsigned short h = f2b(v);
  wT[i] = lo ? f2b(v - b2f(h)) : h;
}

__global__ void k_hist(const int* __restrict__ recv, int* __restrict__ deg){
  int e = blockIdx.x*256 + threadIdx.x;
  if (e < NEg){
    int r = recv[e];
    if ((unsigned)r < NN) atomicAdd(&deg[r], 1);
  }
}

__global__ __launch_bounds__(1024) void k_scan(int* __restrict__ cursor, int* __restrict__ off){
  __shared__ int part[1024];
  int t = threadIdx.x;
  int base = t*20;
  int loc[20]; int s = 0;
  #pragma unroll
  for (int i=0;i<20;i++){ int idx=base+i; int d = (idx<NN)? cursor[idx] : 0; loc[i]=d; s+=d; }
  part[t] = s; __syncthreads();
  for (int d=1; d<1024; d<<=1){
    int v = part[t];
    int add = (t>=d)? part[t-d] : 0;
    __syncthreads();
    part[t] = v + add;
    __syncthreads();
  }
  int run = part[t] - s;
  #pragma unroll
  for (int i=0;i<20;i++){ int idx=base+i; if (idx<NN){ off[idx]=run; cursor[idx]=run; run+=loc[i]; } }
  if (t==1023) off[NN] = part[1023];
}

__global__ void k_fill(const int* __restrict__ recv, int* __restrict__ cursor, int* __restrict__ eid){
  int e = blockIdx.x*256 + threadIdx.x;
  if (e < NEg){
    int r = recv[e];
    if ((unsigned)r < NN){
      int p = atomicAdd(&cursor[r], 1);
      if ((unsigned)p < NEg) eid[p] = e;
    }
  }
}

// up-projection -> sv bf16, interleaved layout [n][u][xs, xv0, xv1, xv2] * 0.125
__global__ __launch_bounds__(256) void k_upproj(const float* __restrict__ nf,
    const unsigned short* __restrict__ wT, unsigned short* __restrict__ sv){
  __shared__ float x[256];
  const unsigned short* W0b = wT + O_W0;
  const unsigned short* W1b = wT + O_W1;
  int n = blockIdx.x, t = threadIdx.x;
  x[t] = nf[n*256 + t];
  __syncthreads();
  float acc = 0.f;
  int slot;
  if (t < 64){
    #pragma unroll 8
    for (int u=0; u<64; u++) acc += x[u] * b2f(W0b[u*64 + t]);
    slot = t*4;
  } else {
    int mm = (t-64) >> 6, vo = (t-64) & 63;
    #pragma unroll 8
    for (int u=0; u<64; u++) acc += x[64 + 3*u + mm] * b2f(W1b[u*64 + vo]);
    slot = vo*4 + 1 + mm;
  }
  sv[n*256 + slot] = f2b(acc * 0.125f);
}

// hi/lo split-activation dense layer (fused fallback only)
__device__ __forceinline__ void dense64_silu(const unsigned short* src,
                                             const unsigned short* WH, const unsigned short* WL,
                                             unsigned short* dst, int m, int q){
  bf16x8 ah0 = *(const bf16x8*)(src + m*72 + q*8);
  bf16x8 ah1 = *(const bf16x8*)(src + m*72 + 32 + q*8);
  bf16x8 al0 = *(const bf16x8*)(src + 1152 + m*72 + q*8);
  bf16x8 al1 = *(const bf16x8*)(src + 1152 + m*72 + 32 + q*8);
  const f32x4 zero = {0.f,0.f,0.f,0.f};
  #pragma unroll
  for (int nt = 0; nt < 4; nt++){
    bf16x8 bh0 = *(const bf16x8*)(WH + (nt*16 + m)*64 + q*8);
    bf16x8 bh1 = *(const bf16x8*)(WH + (nt*16 + m)*64 + 32 + q*8);
    bf16x8 bl0 = *(const bf16x8*)(WL + (nt*16 + m)*64 + q*8);
    bf16x8 bl1 = *(const bf16x8*)(WL + (nt*16 + m)*64 + 32 + q*8);
    f32x4 c = __builtin_amdgcn_mfma_f32_16x16x32_bf16(ah0, bh0, zero, 0, 0, 0);
    c = __builtin_amdgcn_mfma_f32_16x16x32_bf16(ah1, bh1, c, 0, 0, 0);
    c = __builtin_amdgcn_mfma_f32_16x16x32_bf16(al0, bh0, c, 0, 0, 0);
    c = __builtin_amdgcn_mfma_f32_16x16x32_bf16(al1, bh1, c, 0, 0, 0);
    c = __builtin_amdgcn_mfma_f32_16x16x32_bf16(ah0, bl0, c, 0, 0, 0);
    c = __builtin_amdgcn_mfma_f32_16x16x32_bf16(ah1, bl1, c, 0, 0, 0);
    #pragma unroll
    for (int r = 0; r < 4; r++){
      float v = silu_f(c[r] * 0.125f);
      unsigned short hi = f2b(v);
      unsigned short lo = f2b(v - b2f(hi));
      dst[(q*4+r)*72 + nt*16 + m] = hi;
      dst[1152 + (q*4+r)*72 + nt*16 + m] = lo;
    }
  }
}

// hi-only activation dense layer, split weights
__device__ __forceinline__ void dense64h(const unsigned short* src,
                                         const unsigned short* WH, const unsigned short* WL,
                                         unsigned short* dst, int m, int q){
  bf16x8 a0 = *(const bf16x8*)(src + m*72 + q*8);
  bf16x8 a1 = *(const bf16x8*)(src + m*72 + 32 + q*8);
  const f32x4 zero = {0.f,0.f,0.f,0.f};
  #pragma unroll
  for (int nt = 0; nt < 4; nt++){
    bf16x8 bh0 = *(const bf16x8*)(WH + (nt*16 + m)*64 + q*8);
    bf16x8 bh1 = *(const bf16x8*)(WH + (nt*16 + m)*64 + 32 + q*8);
    bf16x8 bl0 = *(const bf16x8*)(WL + (nt*16 + m)*64 + q*8);
    bf16x8 bl1 = *(const bf16x8*)(WL + (nt*16 + m)*64 + 32 + q*8);
    f32x4 c = __builtin_amdgcn_mfma_f32_16x16x32_bf16(a0, bh0, zero, 0, 0, 0);
    c = __builtin_amdgcn_mfma_f32_16x16x32_bf16(a1, bh1, c, 0, 0, 0);
    c = __builtin_amdgcn_mfma_f32_16x16x32_bf16(a0, bl0, c, 0, 0, 0);
    c = __builtin_amdgcn_mfma_f32_16x16x32_bf16(a1, bl1, c, 0, 0, 0);
    #pragma unroll
    for (int r = 0; r < 4; r++)
      dst[(q*4+r)*72 + nt*16 + m] = f2b(silu_f(c[r] * 0.125f));
  }
}

// ---------------- EDGE-LINEAR MLP ----------------
// processes edges [blockIdx*64, +64) directly; no CSR indirection, no guards.
// tpw layout: [e][u][g] interleaved bf16 (slot = u*4+g, channel = g*64+u).
__global__ __launch_bounds__(256) void k_mlp_e(const float* __restrict__ ef,
    const unsigned short* __restrict__ wT, unsigned short* __restrict__ tpw){
  __shared__ __align__(16) unsigned short h[4][1152];   // 9216 B
  const int tid = threadIdx.x;
  const int w = tid >> 6, l = tid & 63;
  const int m = l & 15, q = l >> 4;
  const int e0 = blockIdx.x*64 + w*16;
  const f32x4 zero = {0.f,0.f,0.f,0.f};

  // layer 1: (16x8)@(8x64), K zero-padded to 32, split weights
  bf16x8 a = {0,0,0,0,0,0,0,0};
  if (q == 0){
    const float* efp = ef + (size_t)(e0 + m) * 8;
    float4 fa = *(const float4*)(efp);
    float4 fb = *(const float4*)(efp + 4);
    float av8[8] = {fa.x, fa.y, fa.z, fa.w, fb.x, fb.y, fb.z, fb.w};
    #pragma unroll
    for (int j = 0; j < 8; j++) a[j] = (short)f2b(av8[j]);
  }
  #pragma unroll
  for (int nt = 0; nt < 4; nt++){
    bf16x8 bh = {0,0,0,0,0,0,0,0}, bl = {0,0,0,0,0,0,0,0};
    if (q == 0){
      bh = *(const bf16x8*)(wT + O_M1H + (nt*16 + m)*8);
      bl = *(const bf16x8*)(wT + O_M1L + (nt*16 + m)*8);
    }
    f32x4 c = __builtin_amdgcn_mfma_f32_16x16x32_bf16(a, bh, zero, 0, 0, 0);
    c = __builtin_amdgcn_mfma_f32_16x16x32_bf16(a, bl, c, 0, 0, 0);
    #pragma unroll
    for (int r = 0; r < 4; r++)
      h[w][(q*4+r)*72 + nt*16 + m] = f2b(silu_f(c[r] * 0.35355339059f));
  }
  dense64h(&h[w][0], wT + O_M2H, wT + O_M2L, &h[w][0], m, q);   // layer 2 (in-place)
  dense64h(&h[w][0], wT + O_M3H, wT + O_M3L, &h[w][0], m, q);   // layer 3 (in-place)
  // layer 4: register transpose -> packed ushort4 coalesced stores
  {
    const unsigned short* src = &h[w][0];
    bf16x8 a0 = *(const bf16x8*)(src + m*72 + q*8);
    bf16x8 a1 = *(const bf16x8*)(src + m*72 + 32 + q*8);
    #pragma unroll
    for (int aa = 0; aa < 4; aa++){
      f32x4 cg[4];
      #pragma unroll
      for (int g = 0; g < 4; g++){
        const int nt = g*4 + aa;
        bf16x8 bh0 = *(const bf16x8*)(wT + O_M4H + (nt*16 + m)*64 + q*8);
        bf16x8 bh1 = *(const bf16x8*)(wT + O_M4H + (nt*16 + m)*64 + 32 + q*8);
        bf16x8 bl0 = *(const bf16x8*)(wT + O_M4L + (nt*16 + m)*64 + q*8);
        bf16x8 bl1 = *(const bf16x8*)(wT + O_M4L + (nt*16 + m)*64 + 32 + q*8);
        f32x4 c = __builtin_amdgcn_mfma_f32_16x16x32_bf16(a0, bh0, zero, 0, 0, 0);
        c = __builtin_amdgcn_mfma_f32_16x16x32_bf16(a1, bh1, c, 0, 0, 0);
        c = __builtin_amdgcn_mfma_f32_16x16x32_bf16(a0, bl0, c, 0, 0, 0);
        c = __builtin_amdgcn_mfma_f32_16x16x32_bf16(a1, bl1, c, 0, 0, 0);
        cg[g] = c;
      }
      #pragma unroll
      for (int r = 0; r < 4; r++){
        ushort4 pk;
        pk.x = f2b(cg[0][r] * 0.125f);
        pk.y = f2b(cg[1][r] * 0.125f);
        pk.z = f2b(cg[2][r] * 0.125f);
        pk.w = f2b(cg[3][r] * 0.125f);
        *(ushort4*)(tpw + (size_t)(e0 + q*4 + r)*256 + aa*64 + m*4) = pk;
      }
    }
  }
}

// wave-per-node gather: per edge, ONE uint2 from tpw[e] + ONE uint2 from sv[snd]
__global__ __launch_bounds__(256) void k_gather_s(const int* __restrict__ off, const int* __restrict__ eid,
    const int* __restrict__ sender, const float* __restrict__ ea,
    const unsigned short* __restrict__ sv, const unsigned short* __restrict__ tpw,
    const unsigned short* __restrict__ wT, float* __restrict__ out){
  __shared__ float msg[4][512];
  const int tid = threadIdx.x;
  const int w = tid >> 6, l = tid & 63;
  const int n = blockIdx.x*4 + w;
  int s0 = off[n];
  int cnt = off[n+1] - s0;
  if (s0 < 0) s0 = 0; if (s0 > NEg) s0 = NEg;
  if (cnt < 0) cnt = 0; if (cnt > 512) cnt = 512;
  if (s0 + cnt > NEg) cnt = NEg - s0;

  float as0 = 0.f, as1 = 0.f;
  float av00=0.f, av01=0.f, av02=0.f, av10=0.f, av11=0.f, av12=0.f;

  int e = 0, sd = 0;
  if (cnt > 0){
    e = eid[s0]; if ((unsigned)e >= NEg) e = 0;
    sd = sender[e]; if ((unsigned)sd >= NN) sd = 0;
  }
  for (int i = 0; i < cnt; i++){
    const int ec = e, sc = sd;
    if (i + 1 < cnt){
      e = eid[s0 + i + 1]; if ((unsigned)e >= NEg) e = 0;
      sd = sender[e]; if ((unsigned)sd >= NN) sd = 0;
    }
    const uint2 tw = *(const uint2*)(tpw + (size_t)ec * 256 + l*4);
    const uint2 sx = *(const uint2*)(sv + (size_t)sc * 256 + l*4);
    const float4 ev = *(const float4*)(ea + (size_t)ec * 4);
    const float w0 = blo(tw.x), w1 = bhi(tw.x), w2 = blo(tw.y), w3 = bhi(tw.y);
    const float xs = blo(sx.x), xv0 = bhi(sx.x), xv1 = blo(sx.y), xv2 = bhi(sx.y);
    as0 += w0 * xs * ev.x;
    as1 += w3 * (xv0*ev.y + xv1*ev.z + xv2*ev.w);
    const float t1 = w1 * xs;
    av00 += t1*ev.y; av01 += t1*ev.z; av02 += t1*ev.w;
    const float t2 = w2 * ev.x;
    av10 += t2*xv0; av11 += t2*xv1; av12 += t2*xv2;
  }
  msg[w][l]       = as0;
  msg[w][64 + l]  = as1 * 0.57735026919f;    // INV_SQRT3
  msg[w][128+3*l] = av00; msg[w][128+3*l+1] = av01; msg[w][128+3*l+2] = av02;
  msg[w][320+3*l] = av10; msg[w][320+3*l+1] = av11; msg[w][320+3*l+2] = av12;

  const unsigned short* Wl0b = wT + O_WL0;
  const unsigned short* Wl1b = wT + O_WL1;
  float accS = 0.f, ac0 = 0.f, ac1 = 0.f, ac2 = 0.f;
  #pragma unroll 4
  for (int up = 0; up < 128; up++){
    accS += msg[w][up] * b2f(Wl0b[up*64 + l]);
    const float wv = b2f(Wl1b[up*64 + l]);
    ac0 += msg[w][128 + 3*up]     * wv;
    ac1 += msg[w][128 + 3*up + 1] * wv;
    ac2 += msg[w][128 + 3*up + 2] * wv;
  }
  const float C = 0.0055242717280199f;       // (1/sqrt(128)) / 16
  float* op = out + (size_t)n * 256;
  op[l] = accS * C;
  op[64 + 3*l]     = ac0 * C;
  op[64 + 3*l + 1] = ac1 * C;
  op[64 + 3*l + 2] = ac2 * C;
}

// ---------------- FUSED FALLBACK (small ws) ----------------
__global__ __launch_bounds__(256) void k_fused(const int* __restrict__ off, const int* __restrict__ eid,
    const int* __restrict__ sender, const float* __restrict__ ea,
    const float* __restrict__ ef, const unsigned short* __restrict__ sv,
    const float* __restrict__ nf, const unsigned short* __restrict__ wT,
    float* __restrict__ out, int mode){
  __shared__ __align__(16) unsigned short h[4][2][1152];
  __shared__ __align__(16) unsigned short tpt[4][16][264];
  __shared__ float msg[4][512];
  __shared__ float4 eab[4][16];
  __shared__ int sb[4][16];

  const int tid = threadIdx.x;
  const int w = tid >> 6, l = tid & 63;
  const int m = l & 15, q = l >> 4;
  const int n = blockIdx.x*4 + w;
  const f32x4 zero = {0.f,0.f,0.f,0.f};

  int s0 = off[n];
  int cnt = off[n+1] - s0;
  if (s0 < 0) s0 = 0; if (s0 > NEg) s0 = NEg;
  if (cnt < 0) cnt = 0; if (cnt > 512) cnt = 512;
  if (s0 + cnt > NEg) cnt = NEg - s0;

  float as0 = 0.f, as1 = 0.f;
  float av00=0.f, av01=0.f, av02=0.f, av10=0.f, av11=0.f, av12=0.f;

  const int ntile = (cnt + 15) >> 4;
  for (int tl = 0; tl < ntile; tl++){
    const int base = s0 + tl*16;
    const int rows = min(16, cnt - tl*16);
    bf16x8 ah = {0,0,0,0,0,0,0,0}, al = {0,0,0,0,0,0,0,0};
    if (q == 0){
      int e = 0, sd = 0;
      if (m < rows){
        e = eid[base + m]; if ((unsigned)e >= NEg) e = 0;
        sd = sender[e];    if ((unsigned)sd >= NN) sd = 0;
        const float* efp = ef + (size_t)e * 8;
        float4 fa = *(const float4*)(efp);
        float4 fb = *(const float4*)(efp + 4);
        float av8[8] = {fa.x, fa.y, fa.z, fa.w, fb.x, fb.y, fb.z, fb.w};
        #pragma unroll
        for (int j = 0; j < 8; j++){
          unsigned short hb = f2b(av8[j]);
          ah[j] = (short)hb;
          al[j] = (short)f2b(av8[j] - b2f(hb));
        }
        eab[w][m] = *(const float4*)(ea + (size_t)e * 4);
      }
      sb[w][m] = sd;
    }
    #pragma unroll
    for (int nt = 0; nt < 4; nt++){
      bf16x8 bh = {0,0,0,0,0,0,0,0}, bl = {0,0,0,0,0,0,0,0};
      if (q == 0){
        bh = *(const bf16x8*)(wT + O_M1H + (nt*16 + m)*8);
        bl = *(const bf16x8*)(wT + O_M1L + (nt*16 + m)*8);
      }
      f32x4 c = __builtin_amdgcn_mfma_f32_16x16x32_bf16(ah, bh, zero, 0, 0, 0);
      c = __builtin_amdgcn_mfma_f32_16x16x32_bf16(al, bh, c, 0, 0, 0);
      c = __builtin_amdgcn_mfma_f32_16x16x32_bf16(ah, bl, c, 0, 0, 0);
      #pragma unroll
      for (int r = 0; r < 4; r++){
        float v = silu_f(c[r] * 0.35355339059f);
        unsigned short hi = f2b(v);
        unsigned short lo = f2b(v - b2f(hi));
        h[w][0][(q*4+r)*72 + nt*16 + m] = hi;
        h[w][1][(q*4+r)*72 + nt*16 + m] = lo;
      }
    }
    dense64_silu(&h[w][0][0], wT + O_M2H, wT + O_M2L, &h[w][0][0], m, q);
    dense64_silu(&h[w][0][0], wT + O_M3H, wT + O_M3L, &h[w][0][0], m, q);
    {
      const unsigned short* src = &h[w][0][0];
      bf16x8 ah0 = *(const bf16x8*)(src + m*72 + q*8);
      bf16x8 ah1 = *(const bf16x8*)(src + m*72 + 32 + q*8);
      bf16x8 al0 = *(const bf16x8*)(src + 1152 + m*72 + q*8);
      bf16x8 al1 = *(const bf16x8*)(src + 1152 + m*72 + 32 + q*8);
      #pragma unroll
      for (int nt = 0; nt < 16; nt++){
        bf16x8 bh0 = *(const bf16x8*)(wT + O_M4H + (nt*16 + m)*64 + q*8);
        bf16x8 bh1 = *(const bf16x8*)(wT + O_M4H + (nt*16 + m)*64 + 32 + q*8);
        bf16x8 bl0 = *(const bf16x8*)(wT + O_M4L + (nt*16 + m)*64 + q*8);
        bf16x8 bl1 = *(const bf16x8*)(wT + O_M4L + (nt*16 + m)*64 + 32 + q*8);
        f32x4 c = __builtin_amdgcn_mfma_f32_16x16x32_bf16(ah0, bh0, zero, 0, 0, 0);
        c = __builtin_amdgcn_mfma_f32_16x16x32_bf16(ah1, bh1, c, 0, 0, 0);
        c = __builtin_amdgcn_mfma_f32_16x16x32_bf16(al0, bh0, c, 0, 0, 0);
        c = __builtin_amdgcn_mfma_f32_16x16x32_bf16(al1, bh1, c, 0, 0, 0);
        c = __builtin_amdgcn_mfma_f32_16x16x32_bf16(ah0, bl0, c, 0, 0, 0);
        c = __builtin_amdgcn_mfma_f32_16x16x32_bf16(ah1, bl1, c, 0, 0, 0);
        #pragma unroll
        for (int r = 0; r < 4; r++)
          tpt[w][q*4+r][nt*16 + m] = f2b(c[r] * 0.125f);
      }
    }
    for (int i = 0; i < rows; i++){
      const int sd = sb[w][i];
      const float4 ev = eab[w][i];
      float xs, xv0, xv1, xv2;
      if (mode == 0){
        const uint2 sx = *(const uint2*)(sv + (size_t)sd * 256 + l*4);
        xs = blo(sx.x); xv0 = bhi(sx.x); xv1 = blo(sx.y); xv2 = bhi(sx.y);
      } else {
        const float* nfp = nf + (size_t)sd * 256;
        const unsigned short* W0b = wT + O_W0;
        const unsigned short* W1b = wT + O_W1;
        float a0 = 0.f, a1 = 0.f, a2 = 0.f, a3 = 0.f;
        for (int k = 0; k < 64; k++){
          const float w0k = b2f(W0b[k*64 + l]);
          const float w1k = b2f(W1b[k*64 + l]);
          a0 += nfp[k] * w0k;
          a1 += nfp[64 + 3*k]     * w1k;
          a2 += nfp[64 + 3*k + 1] * w1k;
          a3 += nfp[64 + 3*k + 2] * w1k;
        }
        xs = a0 * 0.125f; xv0 = a1 * 0.125f; xv1 = a2 * 0.125f; xv2 = a3 * 0.125f;
      }
      const float w0 = b2f(tpt[w][i][l]);
      const float w1 = b2f(tpt[w][i][64 + l]);
      const float w2 = b2f(tpt[w][i][128 + l]);
      const float w3 = b2f(tpt[w][i][192 + l]);
      as0 += w0 * xs * ev.x;
      as1 += w3 * (xv0*ev.y + xv1*ev.z + xv2*ev.w);
      const float t1 = w1 * xs;
      av00 += t1*ev.y; av01 += t1*ev.z; av02 += t1*ev.w;
      const float t2 = w2 * ev.x;
      av10 += t2*xv0; av11 += t2*xv1; av12 += t2*xv2;
    }
  }
  msg[w][l]       = as0;
  msg[w][64 + l]  = as1 * 0.57735026919f;
  msg[w][128+3*l] = av00; msg[w][128+3*l+1] = av01; msg[w][128+3*l+2] = av02;
  msg[w][320+3*l] = av10; msg[w][320+3*l+1] = av11; msg[w][320+3*l+2] = av12;

  const unsigned short* Wl0b = wT + O_WL0;
  const unsigned short* Wl1b = wT + O_WL1;
  float accS = 0.f, ac0 = 0.f, ac1 = 0.f, ac2 = 0.f;
  for (int up = 0; up < 128; up++){
    accS += msg[w][up] * b2f(Wl0b[up*64 + l]);
    const float wv = b2f(Wl1b[up*64 + l]);
    ac0 += msg[w][128 + 3*up]     * wv;
    ac1 += msg[w][128 + 3*up + 1] * wv;
    ac2 += msg[w][128 + 3*up + 2] * wv;
  }
  const float C = 0.0055242717280199f;
  float* op = out + (size_t)n * 256;
  op[l] = accS * C;
  op[64 + 3*l]     = ac0 * C;
  op[64 + 3*l + 1] = ac1 * C;
  op[64 + 3*l + 2] = ac2 * C;
}

extern "C" void kernel_launch(void* const* d_in, const int* in_sizes, int n_in,
                              void* d_out, int out_size, void* d_ws, size_t ws_size,
                              hipStream_t stream){
  float* out = (float*)d_out;
  const int nblk_out = (out_size + 255) / 256;

  static const long long exp_sizes[15] = {320000, 5120000, 1280000, 2560000, 640000,
                                          4096, 4096, 512, 4096, 4096, 16384, 8192, 8192,
                                          65536, 65536};
  bool ok = (n_in == 15) && (out_size == 5120000);
  if (ok) for (int i = 0; i < 15; i++) if ((long long)in_sizes[i] != exp_sizes[i]) ok = false;
  if (!ok){
    k_fill32<<<nblk_out, 256, 0, stream>>>(out, out_size, 100.0f);
    return;
  }

  const float* node_feats = (const float*)d_in[1];
  const float* edge_attrs = (const float*)d_in[2];
  const float* edge_feats = (const float*)d_in[3];
  const int* edge_index = (const int*)d_in[4];
  const float* Wup0 = (const float*)d_in[5];
  const float* Wup1 = (const float*)d_in[6];
  const float* M1 = (const float*)d_in[7];
  const float* M2 = (const float*)d_in[8];
  const float* M3 = (const float*)d_in[9];
  const float* M4 = (const float*)d_in[10];
  const float* Wl0 = (const float*)d_in[11];
  const float* Wl1 = (const float*)d_in[12];
  const int* sender = edge_index;
  const int* recv   = edge_index + NEg;

  const size_t SZ_OFF = 80128, SZ_CUR = 80128, SZ_EID = 1280000, SZ_WT = WT_TOT*2;
  const size_t SZ_SV = 10240000;
  const size_t foot_csr  = SZ_OFF + SZ_CUR + SZ_EID + SZ_WT;       // 1,589,760
  const size_t foot_full = foot_csr + SZ_SV;                       // 11,829,760
  const size_t foot_a    = foot_full + (size_t)NEg*512;            // 175,669,760

  if (ws_size < foot_csr){
    k_fill32<<<nblk_out, 256, 0, stream>>>(out, out_size, 50.0f);
    return;
  }
  char* ws = (char*)d_ws;
  int* off    = (int*)(ws);
  int* cursor = (int*)(ws + SZ_OFF);
  int* eid    = (int*)(ws + SZ_OFF + SZ_CUR);
  unsigned short* wT  = (unsigned short*)(ws + SZ_OFF + SZ_CUR + SZ_EID);
  unsigned short* sv  = (unsigned short*)(ws + foot_csr);
  unsigned short* tpw = (unsigned short*)(ws + foot_full);

  k_zero<<<(NN+255)/256, 256, 0, stream>>>(cursor, NN);
  k_prep<<<(WT_TOT+255)/256, 256, 0, stream>>>(M1, M2, M3, M4, Wup0, Wup1, Wl0, Wl1, wT);
  k_hist<<<NEg/256, 256, 0, stream>>>(recv, cursor);
  k_scan<<<1, 1024, 0, stream>>>(cursor, off);
  k_fill<<<NEg/256, 256, 0, stream>>>(recv, cursor, eid);

  if (ws_size >= foot_a){
    k_upproj<<<NN, 256, 0, stream>>>(node_feats, wT, sv);
    k_mlp_e<<<NEg/64, 256, 0, stream>>>(edge_feats, wT, tpw);
    k_gather_s<<<NN/4, 256, 0, stream>>>(off, eid, sender, edge_attrs, sv, tpw, wT, out);
  } else {
    const int mode = (ws_size >= foot_full) ? 0 : 1;
    if (mode == 0)
      k_upproj<<<NN, 256, 0, stream>>>(node_feats, wT, sv);
    k_fused<<<NN/4, 256, 0, stream>>>(off, eid, sender, edge_attrs, edge_feats,
                                      sv, node_feats, wT, out, mode);
  }
}

// Round 11
// 394.874 us; speedup vs baseline: 1.4231x; 1.3724x over previous
//
#include <hip/hip_runtime.h>
#include <hip/hip_bf16.h>
#include <cstdint>

#define NN 20000
#define NEg 320000

typedef short bf16x8 __attribute__((ext_vector_type(8)));
typedef float f32x4 __attribute__((ext_vector_type(4)));

// wT (u16 elements) layout: MLP weights transposed n-major, split hi/lo bf16
#define O_M1H 0
#define O_M1L 512
#define O_M2H 1024
#define O_M2L 5120
#define O_M3H 9216
#define O_M3L 13312
#define O_M4H 17408
#define O_M4L 33792
#define O_W0  50176
#define O_W1  54272
#define O_WL0 58368
#define O_WL1 66560
#define WT_TOT 74752

__device__ __forceinline__ float b2f(unsigned short u){
  unsigned int v = ((unsigned int)u) << 16;
  float f; __builtin_memcpy(&f, &v, 4); return f;
}
__device__ __forceinline__ float blo(unsigned int d){
  unsigned int v = d << 16; float f; __builtin_memcpy(&f, &v, 4); return f;
}
__device__ __forceinline__ float bhi(unsigned int d){
  unsigned int v = d & 0xffff0000u; float f; __builtin_memcpy(&f, &v, 4); return f;
}
__device__ __forceinline__ unsigned short f2b(float f){
  unsigned int x; __builtin_memcpy(&x, &f, 4);
  x += 0x7FFFu + ((x >> 16) & 1u);
  return (unsigned short)(x >> 16);
}
__device__ __forceinline__ float silu_f(float x){ return x / (1.f + __expf(-x)); }

__global__ void k_zero(int* __restrict__ p, int n){
  int i = blockIdx.x*256 + threadIdx.x;
  if (i < n) p[i] = 0;
}

__global__ void k_fill32(float* __restrict__ p, int n, float val){
  int i = blockIdx.x*256 + threadIdx.x;
  if (i < n) p[i] = val;
}

__global__ void k_prep(const float* __restrict__ M1, const float* __restrict__ M2,
                       const float* __restrict__ M3, const float* __restrict__ M4,
                       const float* __restrict__ W0, const float* __restrict__ W1,
                       const float* __restrict__ Wl0, const float* __restrict__ Wl1,
                       unsigned short* __restrict__ wT){
  int i = blockIdx.x*256 + threadIdx.x;
  if (i >= WT_TOT) return;
  float v; bool lo = false;
  if (i < O_M1L){ int t=i;        int n=t>>3, k=t&7;  v = M1[k*64+n]; }
  else if (i < O_M2H){ int t=i-O_M1L; int n=t>>3, k=t&7;  v = M1[k*64+n];  lo = true; }
  else if (i < O_M2L){ int t=i-O_M2H; int n=t>>6, k=t&63; v = M2[k*64+n]; }
  else if (i < O_M3H){ int t=i-O_M2L; int n=t>>6, k=t&63; v = M2[k*64+n]; lo = true; }
  else if (i < O_M3L){ int t=i-O_M3H; int n=t>>6, k=t&63; v = M3[k*64+n]; }
  else if (i < O_M4H){ int t=i-O_M3L; int n=t>>6, k=t&63; v = M3[k*64+n]; lo = true; }
  else if (i < O_M4L){ int t=i-O_M4H; int n=t>>6, k=t&63; v = M4[k*256+n]; }
  else if (i < O_W0 ){ int t=i-O_M4L; int n=t>>6, k=t&63; v = M4[k*256+n]; lo = true; }
  else if (i < O_W1 ){ v = W0[i-O_W0]; }
  else if (i < O_WL0){ v = W1[i-O_W1]; }
  else if (i < O_WL1){ v = Wl0[i-O_WL0]; }
  else               { v = Wl1[i-O_WL1]; }
  unsigned short h = f2b(v);
  wT[i] = lo ? f2b(v - b2f(h)) : h;
}

__global__ void k_hist(const int* __restrict__ recv, int* __restrict__ deg){
  int e = blockIdx.x*256 + threadIdx.x;
  if (e < NEg){
    int r = recv[e];
    if ((unsigned)r < NN) atomicAdd(&deg[r], 1);
  }
}

__global__ __launch_bounds__(1024) void k_scan(int* __restrict__ cursor, int* __restrict__ off){
  __shared__ int part[1024];
  int t = threadIdx.x;
  int base = t*20;
  int loc[20]; int s = 0;
  #pragma unroll
  for (int i=0;i<20;i++){ int idx=base+i; int d = (idx<NN)? cursor[idx] : 0; loc[i]=d; s+=d; }
  part[t] = s; __syncthreads();
  for (int d=1; d<1024; d<<=1){
    int v = part[t];
    int add = (t>=d)? part[t-d] : 0;
    __syncthreads();
    part[t] = v + add;
    __syncthreads();
  }
  int run = part[t] - s;
  #pragma unroll
  for (int i=0;i<20;i++){ int idx=base+i; if (idx<NN){ off[idx]=run; cursor[idx]=run; run+=loc[i]; } }
  if (t==1023) off[NN] = part[1023];
}

__global__ void k_fill(const int* __restrict__ recv, int* __restrict__ cursor, int* __restrict__ eid){
  int e = blockIdx.x*256 + threadIdx.x;
  if (e < NEg){
    int r = recv[e];
    if ((unsigned)r < NN){
      int p = atomicAdd(&cursor[r], 1);
      if ((unsigned)p < NEg) eid[p] = e;
    }
  }
}

// up-projection -> sv bf16, interleaved layout [n][u][xs, xv0, xv1, xv2] * 0.125
__global__ __launch_bounds__(256) void k_upproj(const float* __restrict__ nf,
    const unsigned short* __restrict__ wT, unsigned short* __restrict__ sv){
  __shared__ float x[256];
  const unsigned short* W0b = wT + O_W0;
  const unsigned short* W1b = wT + O_W1;
  int n = blockIdx.x, t = threadIdx.x;
  x[t] = nf[n*256 + t];
  __syncthreads();
  float acc = 0.f;
  int slot;
  if (t < 64){
    #pragma unroll 8
    for (int u=0; u<64; u++) acc += x[u] * b2f(W0b[u*64 + t]);
    slot = t*4;
  } else {
    int mm = (t-64) >> 6, vo = (t-64) & 63;
    #pragma unroll 8
    for (int u=0; u<64; u++) acc += x[64 + 3*u + mm] * b2f(W1b[u*64 + vo]);
    slot = vo*4 + 1 + mm;
  }
  sv[n*256 + slot] = f2b(acc * 0.125f);
}

// hi/lo split-activation dense layer (fused fallback only)
__device__ __forceinline__ void dense64_silu(const unsigned short* src,
                                             const unsigned short* WH, const unsigned short* WL,
                                             unsigned short* dst, int m, int q){
  bf16x8 ah0 = *(const bf16x8*)(src + m*72 + q*8);
  bf16x8 ah1 = *(const bf16x8*)(src + m*72 + 32 + q*8);
  bf16x8 al0 = *(const bf16x8*)(src + 1152 + m*72 + q*8);
  bf16x8 al1 = *(const bf16x8*)(src + 1152 + m*72 + 32 + q*8);
  const f32x4 zero = {0.f,0.f,0.f,0.f};
  #pragma unroll
  for (int nt = 0; nt < 4; nt++){
    bf16x8 bh0 = *(const bf16x8*)(WH + (nt*16 + m)*64 + q*8);
    bf16x8 bh1 = *(const bf16x8*)(WH + (nt*16 + m)*64 + 32 + q*8);
    bf16x8 bl0 = *(const bf16x8*)(WL + (nt*16 + m)*64 + q*8);
    bf16x8 bl1 = *(const bf16x8*)(WL + (nt*16 + m)*64 + 32 + q*8);
    f32x4 c = __builtin_amdgcn_mfma_f32_16x16x32_bf16(ah0, bh0, zero, 0, 0, 0);
    c = __builtin_amdgcn_mfma_f32_16x16x32_bf16(ah1, bh1, c, 0, 0, 0);
    c = __builtin_amdgcn_mfma_f32_16x16x32_bf16(al0, bh0, c, 0, 0, 0);
    c = __builtin_amdgcn_mfma_f32_16x16x32_bf16(al1, bh1, c, 0, 0, 0);
    c = __builtin_amdgcn_mfma_f32_16x16x32_bf16(ah0, bl0, c, 0, 0, 0);
    c = __builtin_amdgcn_mfma_f32_16x16x32_bf16(ah1, bl1, c, 0, 0, 0);
    #pragma unroll
    for (int r = 0; r < 4; r++){
      float v = silu_f(c[r] * 0.125f);
      unsigned short hi = f2b(v);
      unsigned short lo = f2b(v - b2f(hi));
      dst[(q*4+r)*72 + nt*16 + m] = hi;
      dst[1152 + (q*4+r)*72 + nt*16 + m] = lo;
    }
  }
}

// 4-tile dense layer: weights loaded once per nt, applied to 4 activation tiles.
// hw points to this wave's 4 tiles (stride 1152). In-place safe: all A reads precede writes.
__device__ __forceinline__ void dense64x4(unsigned short* hw,
                                          const unsigned short* WH, const unsigned short* WL,
                                          int m, int q){
  bf16x8 a0[4], a1[4];
  #pragma unroll
  for (int t = 0; t < 4; t++){
    a0[t] = *(const bf16x8*)(hw + t*1152 + m*72 + q*8);
    a1[t] = *(const bf16x8*)(hw + t*1152 + m*72 + 32 + q*8);
  }
  const f32x4 zero = {0.f,0.f,0.f,0.f};
  #pragma unroll
  for (int nt = 0; nt < 4; nt++){
    bf16x8 bh0 = *(const bf16x8*)(WH + (nt*16 + m)*64 + q*8);
    bf16x8 bh1 = *(const bf16x8*)(WH + (nt*16 + m)*64 + 32 + q*8);
    bf16x8 bl0 = *(const bf16x8*)(WL + (nt*16 + m)*64 + q*8);
    bf16x8 bl1 = *(const bf16x8*)(WL + (nt*16 + m)*64 + 32 + q*8);
    #pragma unroll
    for (int t = 0; t < 4; t++){
      f32x4 c = __builtin_amdgcn_mfma_f32_16x16x32_bf16(a0[t], bh0, zero, 0, 0, 0);
      c = __builtin_amdgcn_mfma_f32_16x16x32_bf16(a1[t], bh1, c, 0, 0, 0);
      c = __builtin_amdgcn_mfma_f32_16x16x32_bf16(a0[t], bl0, c, 0, 0, 0);
      c = __builtin_amdgcn_mfma_f32_16x16x32_bf16(a1[t], bl1, c, 0, 0, 0);
      #pragma unroll
      for (int r = 0; r < 4; r++)
        hw[t*1152 + (q*4+r)*72 + nt*16 + m] = f2b(silu_f(c[r] * 0.125f));
    }
  }
}

// ---------------- EDGE-LINEAR MLP, 64 edges/wave ----------------
// block = 4 waves x 64 edges = 256 edges; grid = NEg/256 = 1250. No guards, no indirection.
// tpw layout: [e][u][g] interleaved bf16 (slot = u*4+g, channel = g*64+u).
__global__ __launch_bounds__(256) void k_mlp_e(const float* __restrict__ ef,
    const unsigned short* __restrict__ wT, unsigned short* __restrict__ tpw){
  __shared__ __align__(16) unsigned short h[4][4][1152];   // 36864 B: [wave][tile][.]
  const int tid = threadIdx.x;
  const int w = tid >> 6, l = tid & 63;
  const int m = l & 15, q = l >> 4;
  const int e00 = blockIdx.x*256 + w*64;
  const f32x4 zero = {0.f,0.f,0.f,0.f};
  unsigned short* hw = &h[w][0][0];

  // layer 1: (16x8)@(8x64) per tile, K zero-padded to 32; M1 weights loaded once per nt
  {
    bf16x8 a[4];
    #pragma unroll
    for (int t = 0; t < 4; t++){
      bf16x8 z = {0,0,0,0,0,0,0,0};
      a[t] = z;
    }
    if (q == 0){
      #pragma unroll
      for (int t = 0; t < 4; t++){
        const float* efp = ef + (size_t)(e00 + t*16 + m) * 8;
        float4 fa = *(const float4*)(efp);
        float4 fb = *(const float4*)(efp + 4);
        float av8[8] = {fa.x, fa.y, fa.z, fa.w, fb.x, fb.y, fb.z, fb.w};
        #pragma unroll
        for (int j = 0; j < 8; j++) a[t][j] = (short)f2b(av8[j]);
      }
    }
    #pragma unroll
    for (int nt = 0; nt < 4; nt++){
      bf16x8 bh = {0,0,0,0,0,0,0,0}, bl = {0,0,0,0,0,0,0,0};
      if (q == 0){
        bh = *(const bf16x8*)(wT + O_M1H + (nt*16 + m)*8);
        bl = *(const bf16x8*)(wT + O_M1L + (nt*16 + m)*8);
      }
      #pragma unroll
      for (int t = 0; t < 4; t++){
        f32x4 c = __builtin_amdgcn_mfma_f32_16x16x32_bf16(a[t], bh, zero, 0, 0, 0);
        c = __builtin_amdgcn_mfma_f32_16x16x32_bf16(a[t], bl, c, 0, 0, 0);
        #pragma unroll
        for (int r = 0; r < 4; r++)
          hw[t*1152 + (q*4+r)*72 + nt*16 + m] = f2b(silu_f(c[r] * 0.35355339059f));
      }
    }
  }
  dense64x4(hw, wT + O_M2H, wT + O_M2L, m, q);   // layer 2 (in-place, 4 tiles)
  dense64x4(hw, wT + O_M3H, wT + O_M3L, m, q);   // layer 3 (in-place, 4 tiles)
  // layer 4: per aa-group, hold 16 weight frags in regs, apply to 4 tiles; packed ushort4 stores
  #pragma unroll
  for (int aa = 0; aa < 4; aa++){
    bf16x8 wh0[4], wh1[4], wl0[4], wl1[4];
    #pragma unroll
    for (int g = 0; g < 4; g++){
      const int nt = g*4 + aa;
      wh0[g] = *(const bf16x8*)(wT + O_M4H + (nt*16 + m)*64 + q*8);
      wh1[g] = *(const bf16x8*)(wT + O_M4H + (nt*16 + m)*64 + 32 + q*8);
      wl0[g] = *(const bf16x8*)(wT + O_M4L + (nt*16 + m)*64 + q*8);
      wl1[g] = *(const bf16x8*)(wT + O_M4L + (nt*16 + m)*64 + 32 + q*8);
    }
    #pragma unroll
    for (int t = 0; t < 4; t++){
      bf16x8 a0 = *(const bf16x8*)(hw + t*1152 + m*72 + q*8);
      bf16x8 a1 = *(const bf16x8*)(hw + t*1152 + m*72 + 32 + q*8);
      f32x4 cg[4];
      #pragma unroll
      for (int g = 0; g < 4; g++){
        f32x4 c = __builtin_amdgcn_mfma_f32_16x16x32_bf16(a0, wh0[g], zero, 0, 0, 0);
        c = __builtin_amdgcn_mfma_f32_16x16x32_bf16(a1, wh1[g], c, 0, 0, 0);
        c = __builtin_amdgcn_mfma_f32_16x16x32_bf16(a0, wl0[g], c, 0, 0, 0);
        c = __builtin_amdgcn_mfma_f32_16x16x32_bf16(a1, wl1[g], c, 0, 0, 0);
        cg[g] = c;
      }
      #pragma unroll
      for (int r = 0; r < 4; r++){
        ushort4 pk;
        pk.x = f2b(cg[0][r] * 0.125f);
        pk.y = f2b(cg[1][r] * 0.125f);
        pk.z = f2b(cg[2][r] * 0.125f);
        pk.w = f2b(cg[3][r] * 0.125f);
        *(ushort4*)(tpw + (size_t)(e00 + t*16 + q*4 + r)*256 + aa*64 + m*4) = pk;
      }
    }
  }
}

// wave-per-node gather: per edge, ONE uint2 from tpw[e] + ONE uint2 from sv[snd]
__global__ __launch_bounds__(256) void k_gather_s(const int* __restrict__ off, const int* __restrict__ eid,
    const int* __restrict__ sender, const float* __restrict__ ea,
    const unsigned short* __restrict__ sv, const unsigned short* __restrict__ tpw,
    const unsigned short* __restrict__ wT, float* __restrict__ out){
  __shared__ float msg[4][512];
  const int tid = threadIdx.x;
  const int w = tid >> 6, l = tid & 63;
  const int n = blockIdx.x*4 + w;
  int s0 = off[n];
  int cnt = off[n+1] - s0;
  if (s0 < 0) s0 = 0; if (s0 > NEg) s0 = NEg;
  if (cnt < 0) cnt = 0; if (cnt > 512) cnt = 512;
  if (s0 + cnt > NEg) cnt = NEg - s0;

  float as0 = 0.f, as1 = 0.f;
  float av00=0.f, av01=0.f, av02=0.f, av10=0.f, av11=0.f, av12=0.f;

  int e = 0, sd = 0;
  if (cnt > 0){
    e = eid[s0]; if ((unsigned)e >= NEg) e = 0;
    sd = sender[e]; if ((unsigned)sd >= NN) sd = 0;
  }
  for (int i = 0; i < cnt; i++){
    const int ec = e, sc = sd;
    if (i + 1 < cnt){
      e = eid[s0 + i + 1]; if ((unsigned)e >= NEg) e = 0;
      sd = sender[e]; if ((unsigned)sd >= NN) sd = 0;
    }
    const uint2 tw = *(const uint2*)(tpw + (size_t)ec * 256 + l*4);
    const uint2 sx = *(const uint2*)(sv + (size_t)sc * 256 + l*4);
    const float4 ev = *(const float4*)(ea + (size_t)ec * 4);
    const float w0 = blo(tw.x), w1 = bhi(tw.x), w2 = blo(tw.y), w3 = bhi(tw.y);
    const float xs = blo(sx.x), xv0 = bhi(sx.x), xv1 = blo(sx.y), xv2 = bhi(sx.y);
    as0 += w0 * xs * ev.x;
    as1 += w3 * (xv0*ev.y + xv1*ev.z + xv2*ev.w);
    const float t1 = w1 * xs;
    av00 += t1*ev.y; av01 += t1*ev.z; av02 += t1*ev.w;
    const float t2 = w2 * ev.x;
    av10 += t2*xv0; av11 += t2*xv1; av12 += t2*xv2;
  }
  msg[w][l]       = as0;
  msg[w][64 + l]  = as1 * 0.57735026919f;    // INV_SQRT3
  msg[w][128+3*l] = av00; msg[w][128+3*l+1] = av01; msg[w][128+3*l+2] = av02;
  msg[w][320+3*l] = av10; msg[w][320+3*l+1] = av11; msg[w][320+3*l+2] = av12;

  const unsigned short* Wl0b = wT + O_WL0;
  const unsigned short* Wl1b = wT + O_WL1;
  float accS = 0.f, ac0 = 0.f, ac1 = 0.f, ac2 = 0.f;
  #pragma unroll 4
  for (int up = 0; up < 128; up++){
    accS += msg[w][up] * b2f(Wl0b[up*64 + l]);
    const float wv = b2f(Wl1b[up*64 + l]);
    ac0 += msg[w][128 + 3*up]     * wv;
    ac1 += msg[w][128 + 3*up + 1] * wv;
    ac2 += msg[w][128 + 3*up + 2] * wv;
  }
  const float C = 0.0055242717280199f;       // (1/sqrt(128)) / 16
  float* op = out + (size_t)n * 256;
  op[l] = accS * C;
  op[64 + 3*l]     = ac0 * C;
  op[64 + 3*l + 1] = ac1 * C;
  op[64 + 3*l + 2] = ac2 * C;
}

// ---------------- FUSED FALLBACK (small ws) ----------------
__global__ __launch_bounds__(256) void k_fused(const int* __restrict__ off, const int* __restrict__ eid,
    const int* __restrict__ sender, const float* __restrict__ ea,
    const float* __restrict__ ef, const unsigned short* __restrict__ sv,
    const float* __restrict__ nf, const unsigned short* __restrict__ wT,
    float* __restrict__ out, int mode){
  __shared__ __align__(16) unsigned short h[4][2][1152];
  __shared__ __align__(16) unsigned short tpt[4][16][264];
  __shared__ float msg[4][512];
  __shared__ float4 eab[4][16];
  __shared__ int sb[4][16];

  const int tid = threadIdx.x;
  const int w = tid >> 6, l = tid & 63;
  const int m = l & 15, q = l >> 4;
  const int n = blockIdx.x*4 + w;
  const f32x4 zero = {0.f,0.f,0.f,0.f};

  int s0 = off[n];
  int cnt = off[n+1] - s0;
  if (s0 < 0) s0 = 0; if (s0 > NEg) s0 = NEg;
  if (cnt < 0) cnt = 0; if (cnt > 512) cnt = 512;
  if (s0 + cnt > NEg) cnt = NEg - s0;

  float as0 = 0.f, as1 = 0.f;
  float av00=0.f, av01=0.f, av02=0.f, av10=0.f, av11=0.f, av12=0.f;

  const int ntile = (cnt + 15) >> 4;
  for (int tl = 0; tl < ntile; tl++){
    const int base = s0 + tl*16;
    const int rows = min(16, cnt - tl*16);
    bf16x8 ah = {0,0,0,0,0,0,0,0}, al = {0,0,0,0,0,0,0,0};
    if (q == 0){
      int e = 0, sd = 0;
      if (m < rows){
        e = eid[base + m]; if ((unsigned)e >= NEg) e = 0;
        sd = sender[e];    if ((unsigned)sd >= NN) sd = 0;
        const float* efp = ef + (size_t)e * 8;
        float4 fa = *(const float4*)(efp);
        float4 fb = *(const float4*)(efp + 4);
        float av8[8] = {fa.x, fa.y, fa.z, fa.w, fb.x, fb.y, fb.z, fb.w};
        #pragma unroll
        for (int j = 0; j < 8; j++){
          unsigned short hb = f2b(av8[j]);
          ah[j] = (short)hb;
          al[j] = (short)f2b(av8[j] - b2f(hb));
        }
        eab[w][m] = *(const float4*)(ea + (size_t)e * 4);
      }
      sb[w][m] = sd;
    }
    #pragma unroll
    for (int nt = 0; nt < 4; nt++){
      bf16x8 bh = {0,0,0,0,0,0,0,0}, bl = {0,0,0,0,0,0,0,0};
      if (q == 0){
        bh = *(const bf16x8*)(wT + O_M1H + (nt*16 + m)*8);
        bl = *(const bf16x8*)(wT + O_M1L + (nt*16 + m)*8);
      }
      f32x4 c = __builtin_amdgcn_mfma_f32_16x16x32_bf16(ah, bh, zero, 0, 0, 0);
      c = __builtin_amdgcn_mfma_f32_16x16x32_bf16(al, bh, c, 0, 0, 0);
      c = __builtin_amdgcn_mfma_f32_16x16x32_bf16(ah, bl, c, 0, 0, 0);
      #pragma unroll
      for (int r = 0; r < 4; r++){
        float v = silu_f(c[r] * 0.35355339059f);
        unsigned short hi = f2b(v);
        unsigned short lo = f2b(v - b2f(hi));
        h[w][0][(q*4+r)*72 + nt*16 + m] = hi;
        h[w][1][(q*4+r)*72 + nt*16 + m] = lo;
      }
    }
    dense64_silu(&h[w][0][0], wT + O_M2H, wT + O_M2L, &h[w][0][0], m, q);
    dense64_silu(&h[w][0][0], wT + O_M3H, wT + O_M3L, &h[w][0][0], m, q);
    {
      const unsigned short* src = &h[w][0][0];
      bf16x8 ah0 = *(const bf16x8*)(src + m*72 + q*8);
      bf16x8 ah1 = *(const bf16x8*)(src + m*72 + 32 + q*8);
      bf16x8 al0 = *(const bf16x8*)(src + 1152 + m*72 + q*8);
      bf16x8 al1 = *(const bf16x8*)(src + 1152 + m*72 + 32 + q*8);
      #pragma unroll
      for (int nt = 0; nt < 16; nt++){
        bf16x8 bh0 = *(const bf16x8*)(wT + O_M4H + (nt*16 + m)*64 + q*8);
        bf16x8 bh1 = *(const bf16x8*)(wT + O_M4H + (nt*16 + m)*64 + 32 + q*8);
        bf16x8 bl0 = *(const bf16x8*)(wT + O_M4L + (nt*16 + m)*64 + q*8);
        bf16x8 bl1 = *(const bf16x8*)(wT + O_M4L + (nt*16 + m)*64 + 32 + q*8);
        f32x4 c = __builtin_amdgcn_mfma_f32_16x16x32_bf16(ah0, bh0, zero, 0, 0, 0);
        c = __builtin_amdgcn_mfma_f32_16x16x32_bf16(ah1, bh1, c, 0, 0, 0);
        c = __builtin_amdgcn_mfma_f32_16x16x32_bf16(al0, bh0, c, 0, 0, 0);
        c = __builtin_amdgcn_mfma_f32_16x16x32_bf16(al1, bh1, c, 0, 0, 0);
        c = __builtin_amdgcn_mfma_f32_16x16x32_bf16(ah0, bl0, c, 0, 0, 0);
        c = __builtin_amdgcn_mfma_f32_16x16x32_bf16(ah1, bl1, c, 0, 0, 0);
        #pragma unroll
        for (int r = 0; r < 4; r++)
          tpt[w][q*4+r][nt*16 + m] = f2b(c[r] * 0.125f);
      }
    }
    for (int i = 0; i < rows; i++){
      const int sd = sb[w][i];
      const float4 ev = eab[w][i];
      float xs, xv0, xv1, xv2;
      if (mode == 0){
        const uint2 sx = *(const uint2*)(sv + (size_t)sd * 256 + l*4);
        xs = blo(sx.x); xv0 = bhi(sx.x); xv1 = blo(sx.y); xv2 = bhi(sx.y);
      } else {
        const float* nfp = nf + (size_t)sd * 256;
        const unsigned short* W0b = wT + O_W0;
        const unsigned short* W1b = wT + O_W1;
        float a0 = 0.f, a1 = 0.f, a2 = 0.f, a3 = 0.f;
        for (int k = 0; k < 64; k++){
          const float w0k = b2f(W0b[k*64 + l]);
          const float w1k = b2f(W1b[k*64 + l]);
          a0 += nfp[k] * w0k;
          a1 += nfp[64 + 3*k]     * w1k;
          a2 += nfp[64 + 3*k + 1] * w1k;
          a3 += nfp[64 + 3*k + 2] * w1k;
        }
        xs = a0 * 0.125f; xv0 = a1 * 0.125f; xv1 = a2 * 0.125f; xv2 = a3 * 0.125f;
      }
      const float w0 = b2f(tpt[w][i][l]);
      const float w1 = b2f(tpt[w][i][64 + l]);
      const float w2 = b2f(tpt[w][i][128 + l]);
      const float w3 = b2f(tpt[w][i][192 + l]);
      as0 += w0 * xs * ev.x;
      as1 += w3 * (xv0*ev.y + xv1*ev.z + xv2*ev.w);
      const float t1 = w1 * xs;
      av00 += t1*ev.y; av01 += t1*ev.z; av02 += t1*ev.w;
      const float t2 = w2 * ev.x;
      av10 += t2*xv0; av11 += t2*xv1; av12 += t2*xv2;
    }
  }
  msg[w][l]       = as0;
  msg[w][64 + l]  = as1 * 0.57735026919f;
  msg[w][128+3*l] = av00; msg[w][128+3*l+1] = av01; msg[w][128+3*l+2] = av02;
  msg[w][320+3*l] = av10; msg[w][320+3*l+1] = av11; msg[w][320+3*l+2] = av12;

  const unsigned short* Wl0b = wT + O_WL0;
  const unsigned short* Wl1b = wT + O_WL1;
  float accS = 0.f, ac0 = 0.f, ac1 = 0.f, ac2 = 0.f;
  for (int up = 0; up < 128; up++){
    accS += msg[w][up] * b2f(Wl0b[up*64 + l]);
    const float wv = b2f(Wl1b[up*64 + l]);
    ac0 += msg[w][128 + 3*up]     * wv;
    ac1 += msg[w][128 + 3*up + 1] * wv;
    ac2 += msg[w][128 + 3*up + 2] * wv;
  }
  const float C = 0.0055242717280199f;
  float* op = out + (size_t)n * 256;
  op[l] = accS * C;
  op[64 + 3*l]     = ac0 * C;
  op[64 + 3*l + 1] = ac1 * C;
  op[64 + 3*l + 2] = ac2 * C;
}

extern "C" void kernel_launch(void* const* d_in, const int* in_sizes, int n_in,
                              void* d_out, int out_size, void* d_ws, size_t ws_size,
                              hipStream_t stream){
  float* out = (float*)d_out;
  const int nblk_out = (out_size + 255) / 256;

  static const long long exp_sizes[15] = {320000, 5120000, 1280000, 2560000, 640000,
                                          4096, 4096, 512, 4096, 4096, 16384, 8192, 8192,
                                          65536, 65536};
  bool ok = (n_in == 15) && (out_size == 5120000);
  if (ok) for (int i = 0; i < 15; i++) if ((long long)in_sizes[i] != exp_sizes[i]) ok = false;
  if (!ok){
    k_fill32<<<nblk_out, 256, 0, stream>>>(out, out_size, 100.0f);
    return;
  }

  const float* node_feats = (const float*)d_in[1];
  const float* edge_attrs = (const float*)d_in[2];
  const float* edge_feats = (const float*)d_in[3];
  const int* edge_index = (const int*)d_in[4];
  const float* Wup0 = (const float*)d_in[5];
  const float* Wup1 = (const float*)d_in[6];
  const float* M1 = (const float*)d_in[7];
  const float* M2 = (const float*)d_in[8];
  const float* M3 = (const float*)d_in[9];
  const float* M4 = (const float*)d_in[10];
  const float* Wl0 = (const float*)d_in[11];
  const float* Wl1 = (const float*)d_in[12];
  const int* sender = edge_index;
  const int* recv   = edge_index + NEg;

  const size_t SZ_OFF = 80128, SZ_CUR = 80128, SZ_EID = 1280000, SZ_WT = WT_TOT*2;
  const size_t SZ_SV = 10240000;
  const size_t foot_csr  = SZ_OFF + SZ_CUR + SZ_EID + SZ_WT;       // 1,589,760
  const size_t foot_full = foot_csr + SZ_SV;                       // 11,829,760
  const size_t foot_a    = foot_full + (size_t)NEg*512;            // 175,669,760

  if (ws_size < foot_csr){
    k_fill32<<<nblk_out, 256, 0, stream>>>(out, out_size, 50.0f);
    return;
  }
  char* ws = (char*)d_ws;
  int* off    = (int*)(ws);
  int* cursor = (int*)(ws + SZ_OFF);
  int* eid    = (int*)(ws + SZ_OFF + SZ_CUR);
  unsigned short* wT  = (unsigned short*)(ws + SZ_OFF + SZ_CUR + SZ_EID);
  unsigned short* sv  = (unsigned short*)(ws + foot_csr);
  unsigned short* tpw = (unsigned short*)(ws + foot_full);

  k_zero<<<(NN+255)/256, 256, 0, stream>>>(cursor, NN);
  k_prep<<<(WT_TOT+255)/256, 256, 0, stream>>>(M1, M2, M3, M4, Wup0, Wup1, Wl0, Wl1, wT);
  k_hist<<<NEg/256, 256, 0, stream>>>(recv, cursor);
  k_scan<<<1, 1024, 0, stream>>>(cursor, off);
  k_fill<<<NEg/256, 256, 0, stream>>>(recv, cursor, eid);

  if (ws_size >= foot_a){
    k_upproj<<<NN, 256, 0, stream>>>(node_feats, wT, sv);
    k_mlp_e<<<NEg/256, 256, 0, stream>>>(edge_feats, wT, tpw);
    k_gather_s<<<NN/4, 256, 0, stream>>>(off, eid, sender, edge_attrs, sv, tpw, wT, out);
  } else {
    const int mode = (ws_size >= foot_full) ? 0 : 1;
    if (mode == 0)
      k_upproj<<<NN, 256, 0, stream>>>(node_feats, wT, sv);
    k_fused<<<NN/4, 256, 0, stream>>>(off, eid, sender, edge_attrs, edge_feats,
                                      sv, node_feats, wT, out, mode);
  }
}